// Round 1
// baseline (1177.871 us; speedup 1.0000x reference)
//
#include <hip/hip_runtime.h>

#define N_USERS 100000
#define N_ITEMS 50000
#define N_NODES 150000
#define N_EDGES 2400000
#define EMB 64
#define LEAKY 0.3f

// ---------------------------------------------------------------------------
// SpMM (COO, scatter-atomic): one 64-lane wave per edge, lane = feature.
// Gather e[col*64+lane] (256B coalesced) and atomicAdd into t[row*64+lane].
// src is split across two pointers for stage 1 (user_emb ++ item_emb);
// stage 2 passes a single contiguous buffer with src_b == nullptr.
// ---------------------------------------------------------------------------
__global__ __launch_bounds__(256) void spmm_atomic(
    const float* __restrict__ vals,
    const int* __restrict__ rows,
    const int* __restrict__ cols,
    const float* __restrict__ src_a,
    const float* __restrict__ src_b,   // nullptr => src_a is full [N_NODES,64]
    float* __restrict__ dst)
{
    const int tid  = threadIdx.x;
    const int lane = tid & 63;
    const int e    = blockIdx.x * (256 >> 6) + (tid >> 6);
    if (e >= N_EDGES) return;

    const float v = vals[e];
    const int   c = cols[e];
    const int   r = rows[e];

    const float* src;
    if (src_b != nullptr && c >= N_USERS)
        src = src_b + (size_t)(c - N_USERS) * EMB;
    else
        src = src_a + (size_t)c * EMB;

    const float x = v * src[lane];
    unsafeAtomicAdd(&dst[(size_t)r * EMB + lane], x);
}

// ---------------------------------------------------------------------------
// Dense stage: e_out[n,i] = sum_j t[n,j] * W[i,j]  (i.e. t @ W^T), fused with
// LeakyReLU + running 0.25*(e0+e1+e2+e3) accumulation into d_out.
// Block = 256 threads = 16 rows x 64 features (4 row-passes per thread).
// W is staged transposed in LDS, padded to kill bank conflicts.
// ---------------------------------------------------------------------------
template <bool FIRST>
__global__ __launch_bounds__(256) void dense_stage(
    const float* __restrict__ t,        // [N_NODES,64] spmm result
    const float* __restrict__ W,        // [64,64], row-major
    const float* __restrict__ user_emb, // FIRST only
    const float* __restrict__ item_emb, // FIRST only
    float* __restrict__ e2,             // FIRST only: leaky output buffer
    float* __restrict__ out)            // d_out accumulator
{
    __shared__ float wT[64][65];   // wT[j][i] = W[i][j]
    __shared__ float trow[16][64];

    const int tid = threadIdx.x;

    for (int k = tid; k < 64 * 64; k += 256) {
        const int i = k >> 6, j = k & 63;
        wT[j][i] = W[k];
    }

    const int row_base = blockIdx.x * 16;
    for (int k = tid; k < 16 * 64; k += 256) {
        const int r = k >> 6, j = k & 63;
        const int row = row_base + r;
        trow[r][j] = (row < N_NODES) ? t[(size_t)row * EMB + j] : 0.f;
    }
    __syncthreads();

    const int i  = tid & 63;
    const int r0 = tid >> 6;   // 0..3

    #pragma unroll
    for (int rr = 0; rr < 4; ++rr) {
        const int r   = r0 * 4 + rr;
        const int row = row_base + r;
        if (row >= N_NODES) continue;

        float acc = 0.f;
        #pragma unroll
        for (int j = 0; j < 64; ++j)
            acc = fmaf(trow[r][j], wT[j][i], acc);   // trow broadcast, wT conflict-free

        const size_t idx = (size_t)row * EMB + i;
        if (FIRST) {
            const float e1v = acc;
            const float e2v = (e1v >= 0.f) ? e1v : LEAKY * e1v;
            const float e0v = (row < N_USERS)
                                  ? user_emb[idx]
                                  : item_emb[(size_t)(row - N_USERS) * EMB + i];
            e2[idx]  = e2v;
            out[idx] = 0.25f * (e0v + e1v + e2v);
        } else {
            out[idx] += 0.25f * acc;   // + 0.25*e3
        }
    }
}

extern "C" void kernel_launch(void* const* d_in, const int* in_sizes, int n_in,
                              void* d_out, int out_size, void* d_ws, size_t ws_size,
                              hipStream_t stream)
{
    const float* user_emb = (const float*)d_in[0];
    const float* item_emb = (const float*)d_in[1];
    const float* W0       = (const float*)d_in[2];
    const float* W1       = (const float*)d_in[3];
    const float* adj_vals = (const float*)d_in[4];
    const int*   adj_rows = (const int*)d_in[5];
    const int*   adj_cols = (const int*)d_in[6];
    float*       out      = (float*)d_out;

    const size_t mat_bytes = (size_t)N_NODES * EMB * sizeof(float); // 38.4 MB
    float* t  = (float*)d_ws;                        // spmm accumulator
    float* e2 = (float*)((char*)d_ws + mat_bytes);   // leaky output

    const int spmm_blocks  = (N_EDGES + 3) / 4;      // 4 edges per 256-thr block
    const int dense_blocks = (N_NODES + 15) / 16;    // 16 rows per block

    // ---- stage 1: t = A @ e0 -------------------------------------------------
    hipMemsetAsync(t, 0, mat_bytes, stream);
    spmm_atomic<<<spmm_blocks, 256, 0, stream>>>(
        adj_vals, adj_rows, adj_cols, user_emb, item_emb, t);

    // ---- e1 = t @ W0^T; e2 = leaky(e1); out = 0.25*(e0+e1+e2) ---------------
    dense_stage<true><<<dense_blocks, 256, 0, stream>>>(
        t, W0, user_emb, item_emb, e2, out);

    // ---- stage 2: t = A @ e2 -------------------------------------------------
    hipMemsetAsync(t, 0, mat_bytes, stream);
    spmm_atomic<<<spmm_blocks, 256, 0, stream>>>(
        adj_vals, adj_rows, adj_cols, e2, nullptr, t);

    // ---- e3 = t @ W1^T; out += 0.25*e3 --------------------------------------
    dense_stage<false><<<dense_blocks, 256, 0, stream>>>(
        t, W1, nullptr, nullptr, nullptr, out);
}

// Round 2
// 618.879 us; speedup vs baseline: 1.9032x; 1.9032x over previous
//
#include <hip/hip_runtime.h>

#define N_USERS 100000
#define N_ITEMS 50000
#define N_NODES 150000
#define N_EDGES 2400000
#define EMB 64
#define LEAKY 0.3f

#define SCAN_CHUNK 1024
#define NBLK ((N_NODES + SCAN_CHUNK - 1) / SCAN_CHUNK)   // 147

// ===========================================================================
// CSR build: histogram -> hierarchical exclusive scan -> scatter
// ===========================================================================
__global__ __launch_bounds__(256) void hist_kernel(
    const int* __restrict__ rows, int* __restrict__ cnt)
{
    const int i = blockIdx.x * 256 + threadIdx.x;
    if (i < N_EDGES) atomicAdd(&cnt[rows[i]], 1);
}

// per-1024-chunk sums
__global__ __launch_bounds__(256) void scan_partial(
    const int* __restrict__ cnt, int* __restrict__ blk_sums)
{
    __shared__ int lds[256];
    const int b = blockIdx.x, t = threadIdx.x;
    const int base = b * SCAN_CHUNK + t * 4;
    int s = 0;
    #pragma unroll
    for (int j = 0; j < 4; ++j) {
        const int idx = base + j;
        if (idx < N_NODES) s += cnt[idx];
    }
    lds[t] = s;
    __syncthreads();
    for (int off = 128; off > 0; off >>= 1) {
        if (t < off) lds[t] += lds[t + off];
        __syncthreads();
    }
    if (t == 0) blk_sums[b] = lds[0];
}

// exclusive scan of the NBLK chunk sums (single block)
__global__ __launch_bounds__(256) void scan_blk(
    const int* __restrict__ blk_sums, int* __restrict__ blk_offs)
{
    __shared__ int lds[256];
    const int t = threadIdx.x;
    const int v = (t < NBLK) ? blk_sums[t] : 0;
    lds[t] = v;
    __syncthreads();
    for (int off = 1; off < 256; off <<= 1) {
        int x = 0;
        if (t >= off) x = lds[t - off];
        __syncthreads();
        lds[t] += x;
        __syncthreads();
    }
    if (t < NBLK) blk_offs[t] = lds[t] - v;   // exclusive
}

// per-chunk exclusive scan + chunk offset -> row_ptr (and heads copy)
__global__ __launch_bounds__(256) void scan_apply(
    const int* __restrict__ cnt, const int* __restrict__ blk_offs,
    int* __restrict__ row_ptr, int* __restrict__ heads)
{
    __shared__ int lds[256];
    const int b = blockIdx.x, t = threadIdx.x;
    const int base = b * SCAN_CHUNK + t * 4;
    int v[4];
    int s = 0;
    #pragma unroll
    for (int j = 0; j < 4; ++j) {
        const int idx = base + j;
        v[j] = (idx < N_NODES) ? cnt[idx] : 0;
        s += v[j];
    }
    lds[t] = s;
    __syncthreads();
    for (int off = 1; off < 256; off <<= 1) {
        int x = 0;
        if (t >= off) x = lds[t - off];
        __syncthreads();
        lds[t] += x;
        __syncthreads();
    }
    int run = blk_offs[b] + (lds[t] - s);   // exclusive prefix for this thread
    #pragma unroll
    for (int j = 0; j < 4; ++j) {
        const int idx = base + j;
        if (idx < N_NODES) {
            row_ptr[idx] = run;
            heads[idx]   = run;
            run += v[j];
        }
    }
}

// scatter edges into row-sorted order; (val, col) interleaved as float2
__global__ __launch_bounds__(256) void scatter_kernel(
    const float* __restrict__ vals, const int* __restrict__ rows,
    const int* __restrict__ cols, int* __restrict__ heads,
    float2* __restrict__ sedge)
{
    const int i = blockIdx.x * 256 + threadIdx.x;
    if (i >= N_EDGES) return;
    const int r   = rows[i];
    const int pos = atomicAdd(&heads[r], 1);
    sedge[pos] = make_float2(vals[i], __int_as_float(cols[i]));
}
// after scatter, heads[r] == row_ptr[r] + degree(r) == row end

// ===========================================================================
// Pull-SpMM: one wave per destination row; register accumulate; no atomics.
// ===========================================================================
__device__ __forceinline__ const float* src_row(
    const float* __restrict__ src_a, const float* __restrict__ src_b, int c)
{
    if (src_b != nullptr && c >= N_USERS)
        return src_b + (size_t)(c - N_USERS) * EMB;
    return src_a + (size_t)c * EMB;
}

__global__ __launch_bounds__(256) void spmm_csr(
    const int* __restrict__ row_beg, const int* __restrict__ row_end,
    const float2* __restrict__ sedge,
    const float* __restrict__ src_a,
    const float* __restrict__ src_b,   // nullptr => src_a is full [N_NODES,64]
    float* __restrict__ dst)
{
    const int lane = threadIdx.x & 63;
    const int row  = (blockIdx.x * 256 + threadIdx.x) >> 6;
    if (row >= N_NODES) return;

    const int beg = row_beg[row];
    const int end = row_end[row];

    float a0 = 0.f, a1 = 0.f, a2 = 0.f, a3 = 0.f;
    int k = beg;
    for (; k + 4 <= end; k += 4) {
        const float2 e0 = sedge[k + 0];
        const float2 e1 = sedge[k + 1];
        const float2 e2 = sedge[k + 2];
        const float2 e3 = sedge[k + 3];
        const float* s0 = src_row(src_a, src_b, __float_as_int(e0.y));
        const float* s1 = src_row(src_a, src_b, __float_as_int(e1.y));
        const float* s2 = src_row(src_a, src_b, __float_as_int(e2.y));
        const float* s3 = src_row(src_a, src_b, __float_as_int(e3.y));
        const float x0 = s0[lane], x1 = s1[lane], x2 = s2[lane], x3 = s3[lane];
        a0 = fmaf(e0.x, x0, a0);
        a1 = fmaf(e1.x, x1, a1);
        a2 = fmaf(e2.x, x2, a2);
        a3 = fmaf(e3.x, x3, a3);
    }
    for (; k < end; ++k) {
        const float2 e = sedge[k];
        const float* s = src_row(src_a, src_b, __float_as_int(e.y));
        a0 = fmaf(e.x, s[lane], a0);
    }
    dst[(size_t)row * EMB + lane] = (a0 + a1) + (a2 + a3);
}

// ===========================================================================
// Fallback atomic SpMM (round-1 proven) — used only if ws too small for CSR.
// ===========================================================================
__global__ __launch_bounds__(256) void spmm_atomic(
    const float* __restrict__ vals, const int* __restrict__ rows,
    const int* __restrict__ cols, const float* __restrict__ src_a,
    const float* __restrict__ src_b, float* __restrict__ dst)
{
    const int tid  = threadIdx.x;
    const int lane = tid & 63;
    const int e    = blockIdx.x * 4 + (tid >> 6);
    if (e >= N_EDGES) return;
    const float v = vals[e];
    const int   c = cols[e];
    const int   r = rows[e];
    const float* src = src_row(src_a, src_b, c);
    unsafeAtomicAdd(&dst[(size_t)r * EMB + lane], v * src[lane]);
}

// ===========================================================================
// Dense stage: e_out = t @ W^T, fused with LeakyReLU + 0.25-mean accumulation.
// ===========================================================================
template <bool FIRST>
__global__ __launch_bounds__(256) void dense_stage(
    const float* __restrict__ t, const float* __restrict__ W,
    const float* __restrict__ user_emb, const float* __restrict__ item_emb,
    float* __restrict__ e2, float* __restrict__ out)
{
    __shared__ float wT[64][65];
    __shared__ float trow[16][64];

    const int tid = threadIdx.x;
    for (int k = tid; k < 64 * 64; k += 256) {
        const int i = k >> 6, j = k & 63;
        wT[j][i] = W[k];
    }
    const int row_base = blockIdx.x * 16;
    for (int k = tid; k < 16 * 64; k += 256) {
        const int r = k >> 6, j = k & 63;
        const int row = row_base + r;
        trow[r][j] = (row < N_NODES) ? t[(size_t)row * EMB + j] : 0.f;
    }
    __syncthreads();

    const int i  = tid & 63;
    const int r0 = tid >> 6;

    #pragma unroll
    for (int rr = 0; rr < 4; ++rr) {
        const int r   = r0 * 4 + rr;
        const int row = row_base + r;
        if (row >= N_NODES) continue;

        float acc = 0.f;
        #pragma unroll
        for (int j = 0; j < 64; ++j)
            acc = fmaf(trow[r][j], wT[j][i], acc);

        const size_t idx = (size_t)row * EMB + i;
        if (FIRST) {
            const float e1v = acc;
            const float e2v = (e1v >= 0.f) ? e1v : LEAKY * e1v;
            const float e0v = (row < N_USERS)
                                  ? user_emb[idx]
                                  : item_emb[(size_t)(row - N_USERS) * EMB + i];
            e2[idx]  = e2v;
            out[idx] = 0.25f * (e0v + e1v + e2v);
        } else {
            out[idx] += 0.25f * acc;
        }
    }
}

// ===========================================================================
extern "C" void kernel_launch(void* const* d_in, const int* in_sizes, int n_in,
                              void* d_out, int out_size, void* d_ws, size_t ws_size,
                              hipStream_t stream)
{
    const float* user_emb = (const float*)d_in[0];
    const float* item_emb = (const float*)d_in[1];
    const float* W0       = (const float*)d_in[2];
    const float* W1       = (const float*)d_in[3];
    const float* adj_vals = (const float*)d_in[4];
    const int*   adj_rows = (const int*)d_in[5];
    const int*   adj_cols = (const int*)d_in[6];
    float*       out      = (float*)d_out;

    const size_t mat_bytes   = (size_t)N_NODES * EMB * sizeof(float);  // 38.4 MB
    const size_t edge_bytes  = (size_t)N_EDGES * sizeof(float2);       // 19.2 MB
    const size_t node_ints   = (size_t)N_NODES * sizeof(int);          // 0.6 MB
    const size_t blk_bytes   = 1024;

    const size_t off_t      = 0;
    const size_t off_e2     = off_t + mat_bytes;
    const size_t off_sedge  = off_e2 + mat_bytes;
    const size_t off_cnt    = off_sedge + edge_bytes;
    const size_t off_rowptr = off_cnt + node_ints;
    const size_t off_heads  = off_rowptr + node_ints;
    const size_t off_bsums  = off_heads + node_ints;
    const size_t off_boffs  = off_bsums + blk_bytes;
    const size_t required   = off_boffs + blk_bytes;

    const int edge_blocks  = (N_EDGES + 255) / 256;        // 9375
    const int dense_blocks = (N_NODES + 15) / 16;          // 9375
    const int row_blocks   = (N_NODES * 64 + 255) / 256;   // 37500 (4 rows/block)

    if (ws_size >= required) {
        // ------------------- CSR path -------------------
        float*  t       = (float*)((char*)d_ws + off_t);
        float*  e2      = (float*)((char*)d_ws + off_e2);
        float2* sedge   = (float2*)((char*)d_ws + off_sedge);
        int*    cnt     = (int*)((char*)d_ws + off_cnt);
        int*    row_ptr = (int*)((char*)d_ws + off_rowptr);
        int*    heads   = (int*)((char*)d_ws + off_heads);
        int*    bsums   = (int*)((char*)d_ws + off_bsums);
        int*    boffs   = (int*)((char*)d_ws + off_boffs);

        // build CSR once, reuse for both SpMMs
        hipMemsetAsync(cnt, 0, node_ints, stream);
        hist_kernel<<<edge_blocks, 256, 0, stream>>>(adj_rows, cnt);
        scan_partial<<<NBLK, 256, 0, stream>>>(cnt, bsums);
        scan_blk<<<1, 256, 0, stream>>>(bsums, boffs);
        scan_apply<<<NBLK, 256, 0, stream>>>(cnt, boffs, row_ptr, heads);
        scatter_kernel<<<edge_blocks, 256, 0, stream>>>(
            adj_vals, adj_rows, adj_cols, heads, sedge);
        // heads[r] is now row end

        // stage 1: t = A @ e0
        spmm_csr<<<row_blocks, 256, 0, stream>>>(
            row_ptr, heads, sedge, user_emb, item_emb, t);
        dense_stage<true><<<dense_blocks, 256, 0, stream>>>(
            t, W0, user_emb, item_emb, e2, out);

        // stage 2: t = A @ e2
        spmm_csr<<<row_blocks, 256, 0, stream>>>(
            row_ptr, heads, sedge, e2, nullptr, t);
        dense_stage<false><<<dense_blocks, 256, 0, stream>>>(
            t, W1, nullptr, nullptr, nullptr, out);
    } else {
        // ------------------- fallback: atomic path (round 1) -------------------
        float* t  = (float*)d_ws;
        float* e2 = (float*)((char*)d_ws + mat_bytes);

        hipMemsetAsync(t, 0, mat_bytes, stream);
        spmm_atomic<<<(N_EDGES + 3) / 4, 256, 0, stream>>>(
            adj_vals, adj_rows, adj_cols, user_emb, item_emb, t);
        dense_stage<true><<<dense_blocks, 256, 0, stream>>>(
            t, W0, user_emb, item_emb, e2, out);

        hipMemsetAsync(t, 0, mat_bytes, stream);
        spmm_atomic<<<(N_EDGES + 3) / 4, 256, 0, stream>>>(
            adj_vals, adj_rows, adj_cols, e2, nullptr, t);
        dense_stage<false><<<dense_blocks, 256, 0, stream>>>(
            t, W1, nullptr, nullptr, nullptr, out);
    }
}